// Round 5
// baseline (1113.571 us; speedup 1.0000x reference)
//
#include <hip/hip_runtime.h>

#define N_NODES 50000
#define N_EDGES 800000

// ------------------------------- CSR build ----------------------------------
__global__ void __launch_bounds__(256) count_kernel(const int* __restrict__ dst,
                                                    int* __restrict__ counts) {
  int e = blockIdx.x * 256 + threadIdx.x;
  if (e < N_EDGES) atomicAdd(&counts[dst[e]], 1);
}

__global__ void __launch_bounds__(1024) scan_kernel(int* __restrict__ counts,
                                                    int* __restrict__ offsets) {
  __shared__ int ps[1024];
  const int PER = (N_NODES + 1023) / 1024;  // 49
  int tid = threadIdx.x;
  int base = tid * PER;
  int s = 0;
  for (int i = 0; i < PER; ++i) {
    int idx = base + i;
    if (idx < N_NODES) s += counts[idx];
  }
  ps[tid] = s;
  __syncthreads();
  for (int off = 1; off < 1024; off <<= 1) {
    int t = (tid >= off) ? ps[tid - off] : 0;
    __syncthreads();
    ps[tid] += t;
    __syncthreads();
  }
  int run = ps[tid] - s;
  for (int i = 0; i < PER; ++i) {
    int idx = base + i;
    if (idx < N_NODES) {
      int c = counts[idx];
      offsets[idx] = run;
      counts[idx] = run;  // cursor for scatter
      run += c;
    }
  }
  if (tid == 1023) offsets[N_NODES] = ps[1023];
}

__global__ void __launch_bounds__(256) scatter_kernel(
    const int* __restrict__ src, const int* __restrict__ dst,
    int* __restrict__ cursor, int2* __restrict__ csr) {
  int e = blockIdx.x * 256 + threadIdx.x;
  if (e >= N_EDGES) return;
  int d = dst[e];
  int slot = atomicAdd(&cursor[d], 1);
  csr[slot] = make_int2(src[e], d);   // one 8B store, one cacheline
}

// ---------------- weight pre-transposes into workspace -----------------------
// wbuf layout (floats):
//   [0,8192)      w1tT  : tW1 [64][128] -> [128][64]
//   [8192,16384)  pW1T  : pW1 [64][128] -> [128][64]
//   [16384,18432) thWT  : thW [32][64]  -> [64][32]
//   [18432,20480) phWT  : phW [32][64]  -> [64][32]
//   [20480,22528) tW0T  : tW0 [32][64]  -> [64][32]
//   [22528,24576) pW0T  : pW0 [32][64]  -> [64][32]
//   [24576,26624) pW3T  : pW3 [32][64]  -> [64][32]
constexpr int WB_W1T  = 0;
constexpr int WB_PW1T = 8192;
constexpr int WB_THWT = 16384;
constexpr int WB_PHWT = 18432;
constexpr int WB_TW0T = 20480;
constexpr int WB_PW0T = 22528;
constexpr int WB_PW3T = 24576;
constexpr int WB_SZ   = 26624;

__global__ void __launch_bounds__(256) prep_kernel(
    const float* __restrict__ tW1, const float* __restrict__ pW1,
    const float* __restrict__ thW, const float* __restrict__ phW,
    const float* __restrict__ tW0, const float* __restrict__ pW0,
    const float* __restrict__ pW3, float* __restrict__ wbuf) {
  int t = blockIdx.x * 256 + threadIdx.x;
  if (t < 16384) {  // 128x64 transposes
    int base = (t < 8192) ? 0 : 8192;
    const float* W = (t < 8192) ? tW1 : pW1;
    int tt = t - base;
    int k2 = tt >> 6, j = tt & 63;
    wbuf[base + tt] = W[j * 128 + k2];
  } else if (t < WB_SZ) {  // 64x32 transposes
    int which = (t - 16384) >> 11;       // 0..4
    int tt = (t - 16384) & 2047;
    const float* W = (which == 0) ? thW : (which == 1) ? phW
                   : (which == 2) ? tW0 : (which == 3) ? pW0 : pW3;
    int j = tt >> 5, k = tt & 31;
    wbuf[16384 + (which << 11) + tt] = W[k * 64 + j];
  }
}

// ------------------------------ node kernels ---------------------------------
// Split into two block ranges (uniform per block, no divergence):
//   blocks [0, NBX)        : x-path  -> out[n][0:64]=a, gp[n][0:64]=g
//   blocks [NBX, 2*NBX)    : en-path -> u[n], gp[n][64:128]=pen
// All weights read as wave-uniform scalar rows (s_load) — zero LDS.
#define NBX 98

__global__ void __launch_bounds__(512) node_kernel(
    const float* __restrict__ x, const float* __restrict__ en,
    const float* __restrict__ wbuf,
    const float* __restrict__ thB, const float* __restrict__ phB,
    const float* __restrict__ pb0, const float* __restrict__ pb1,
    const float* __restrict__ pW2, const float* __restrict__ pb2,
    const float* __restrict__ pb3,
    float* __restrict__ out, float* __restrict__ gp, float* __restrict__ u) {
  const int tid = threadIdx.x;
  const bool enPath = blockIdx.x >= NBX;
  const int nb = blockIdx.x - (enPath ? NBX : 0);
  const int n = nb * 512 + tid;
  if (n >= N_NODES) return;

  if (!enPath) {
    // ---------------- x path ----------------
    float xv[32];
    {
      const float4* p = (const float4*)(x + (long)n * 32);
#pragma unroll
      for (int q = 0; q < 8; ++q) {
        float4 v = p[q];
        xv[q * 4 + 0] = v.x; xv[q * 4 + 1] = v.y;
        xv[q * 4 + 2] = v.z; xv[q * 4 + 3] = v.w;
      }
    }
    const float* thWT = wbuf + WB_THWT;
    const float* phWT = wbuf + WB_PHWT;
    float* ao = out + (long)n * 128;
    float* go = gp + (long)n * 128;
    for (int j4 = 0; j4 < 16; ++j4) {
      float av[4], gv[4];
#pragma unroll
      for (int r = 0; r < 4; ++r) {
        int j = j4 * 4 + r;
        const float* tr = thWT + j * 32;
        const float* pr = phWT + j * 32;
        float t0 = 0.f, t1 = 0.f, p0 = 0.f, p1 = 0.f;
#pragma unroll
        for (int k = 0; k < 16; ++k) {
          t0 += xv[k] * tr[k];
          t1 += xv[k + 16] * tr[k + 16];
          p0 += xv[k] * pr[k];
          p1 += xv[k + 16] * pr[k + 16];
        }
        float dth = t0 + t1, dph = p0 + p1;
        av[r] = thB[j] + dth;
        gv[r] = phB[j] + dph - dth;
      }
      *(float4*)(ao + j4 * 4) = make_float4(av[0], av[1], av[2], av[3]);
      *(float4*)(go + j4 * 4) = make_float4(gv[0], gv[1], gv[2], gv[3]);
    }
  } else {
    // ---------------- en path ----------------
    float ev[32];
    {
      const float4* p = (const float4*)(en + (long)n * 32);
#pragma unroll
      for (int q = 0; q < 8; ++q) {
        float4 v = p[q];
        ev[q * 4 + 0] = v.x; ev[q * 4 + 1] = v.y;
        ev[q * 4 + 2] = v.z; ev[q * 4 + 3] = v.w;
      }
    }
    // u[n] = en @ tW0
    const float* tW0T = wbuf + WB_TW0T;
    float* uo = u + (long)n * 64;
    for (int j4 = 0; j4 < 16; ++j4) {
      float uv[4];
#pragma unroll
      for (int r = 0; r < 4; ++r) {
        int j = j4 * 4 + r;
        const float* wr = tW0T + j * 32;
        float a0 = 0.f, a1 = 0.f;
#pragma unroll
        for (int k = 0; k < 16; ++k) {
          a0 += ev[k] * wr[k];
          a1 += ev[k + 16] * wr[k + 16];
        }
        uv[r] = a0 + a1;
      }
      *(float4*)(uo + j4 * 4) = make_float4(uv[0], uv[1], uv[2], uv[3]);
    }
    // pen MLP layer 0
    const float* pW0T = wbuf + WB_PW0T;
    float h0[64];
#pragma unroll 4
    for (int j = 0; j < 64; ++j) {
      const float* wr = pW0T + j * 32;
      float a0 = pb0[j], a1 = 0.f;
#pragma unroll
      for (int k = 0; k < 16; ++k) {
        a0 += ev[k] * wr[k];
        a1 += ev[k + 16] * wr[k + 16];
      }
      h0[j] = fmaxf(a0 + a1, 0.f);
    }
    // layers 1,2 (k2-outer, scalar rows)
    const float* pW1T = wbuf + WB_PW1T;
    float h2[32];
#pragma unroll
    for (int c = 0; c < 32; ++c) h2[c] = pb2[c];
#pragma unroll 2
    for (int k2 = 0; k2 < 128; ++k2) {
      const float* wr = pW1T + k2 * 64;
      float t0 = pb1[k2], t1 = 0.f, t2 = 0.f, t3 = 0.f;
#pragma unroll
      for (int j = 0; j < 16; ++j) {
        t0 += h0[j] * wr[j];
        t1 += h0[j + 16] * wr[j + 16];
        t2 += h0[j + 32] * wr[j + 32];
        t3 += h0[j + 48] * wr[j + 48];
      }
      float t = fmaxf((t0 + t1) + (t2 + t3), 0.f);
      const float* w2r = pW2 + k2 * 32;
#pragma unroll
      for (int c = 0; c < 32; ++c) h2[c] += t * w2r[c];
    }
#pragma unroll
    for (int c = 0; c < 32; ++c) h2[c] = fmaxf(h2[c], 0.f);
    // layer 3 -> pen
    const float* pW3T = wbuf + WB_PW3T;
    float* go = gp + (long)n * 128 + 64;
    for (int j4 = 0; j4 < 16; ++j4) {
      float ov[4];
#pragma unroll
      for (int r = 0; r < 4; ++r) {
        int j = j4 * 4 + r;
        const float* wr = pW3T + j * 32;
        float a0 = pb3[j], a1 = 0.f;
#pragma unroll
        for (int k = 0; k < 16; ++k) {
          a0 += h2[k] * wr[k];
          a1 += h2[k + 16] * wr[k + 16];
        }
        ov[r] = a0 + a1;
      }
      *(float4*)(go + j4 * 4) = make_float4(ov[0], ov[1], ov[2], ov[3]);
    }
  }
}

// -------- per-edge theta MLP (layers 1,2) — scalar (SGPR) weights ------------
// (round-3 structure: 1 edge/thread, VGPR 64, zero LDS)
__device__ __forceinline__ void seg_reduce(int d, bool valid, float h2[32],
                                           float* __restrict__ h2sum) {
  int lane = threadIdx.x & 63;
  int dprev = __shfl_up(d, 1);
  bool head = (lane == 0) || (dprev != d);
  int seg = head ? lane : 0;
#pragma unroll
  for (int off = 1; off < 64; off <<= 1) {
    int t = __shfl_up(seg, off);
    if (lane >= off) seg = max(seg, t);
  }
#pragma unroll
  for (int off = 1; off < 64; off <<= 1) {
    bool take = (lane - off) >= seg;
#pragma unroll
    for (int k = 0; k < 32; ++k) {
      float t = __shfl_up(h2[k], off);
      h2[k] += take ? t : 0.f;
    }
  }
  int dnext = __shfl_down(d, 1);
  bool tail = (lane == 63) || (dnext != d);
  if (valid && tail) {
    float* hs = h2sum + (long)d * 32;
#pragma unroll
    for (int k = 0; k < 32; ++k) atomicAdd(&hs[k], h2[k]);
  }
}

__global__ void __launch_bounds__(256) mlp_edge_kernel(
    const float* __restrict__ u,
    const int2* __restrict__ csr,
    const float* __restrict__ b0g,
    const float* __restrict__ W1T,   // [128][64] pre-transposed (in ws)
    const float* __restrict__ b1g,
    const float* __restrict__ W2,    // [128][32] natural
    const float* __restrict__ b2g,
    float* __restrict__ h2sum) {
  long slot = (long)blockIdx.x * 256 + threadIdx.x;
  const bool valid = slot < N_EDGES;
  const int2 p = csr[valid ? slot : 0];
  const int s = p.x, d = p.y;

  // h0 = relu(u[d] - u[s] + b0)   (b0 reads are wave-uniform -> SGPR)
  float h0[64];
  {
    const float4* ud4 = (const float4*)(u + (long)d * 64);
    const float4* us4 = (const float4*)(u + (long)s * 64);
#pragma unroll
    for (int q = 0; q < 16; ++q) {
      float4 a = ud4[q], b = us4[q];
      h0[q * 4 + 0] = fmaxf(a.x - b.x + b0g[q * 4 + 0], 0.f);
      h0[q * 4 + 1] = fmaxf(a.y - b.y + b0g[q * 4 + 1], 0.f);
      h0[q * 4 + 2] = fmaxf(a.z - b.z + b0g[q * 4 + 2], 0.f);
      h0[q * 4 + 3] = fmaxf(a.w - b.w + b0g[q * 4 + 3], 0.f);
    }
  }

  float h2[32];
#pragma unroll
  for (int c = 0; c < 32; ++c) h2[c] = b2g[c];

  // k2-outer: W1T row (256B) and W2 row (128B) are contiguous, wave-uniform
  // -> s_load_dwordx16 on the scalar pipe; zero LDS traffic.
#pragma unroll 2
  for (int k2 = 0; k2 < 128; ++k2) {
    const float* wr = W1T + k2 * 64;
    float t0 = b1g[k2], t1 = 0.f, t2 = 0.f, t3 = 0.f;
#pragma unroll
    for (int j = 0; j < 16; ++j) {
      t0 += h0[j]      * wr[j];
      t1 += h0[j + 16] * wr[j + 16];
      t2 += h0[j + 32] * wr[j + 32];
      t3 += h0[j + 48] * wr[j + 48];
    }
    float t = fmaxf((t0 + t1) + (t2 + t3), 0.f);
    const float* w2r = W2 + k2 * 32;
#pragma unroll
    for (int c = 0; c < 32; ++c) h2[c] += t * w2r[c];
  }

#pragma unroll
  for (int c = 0; c < 32; ++c) h2[c] = valid ? fmaxf(h2[c], 0.f) : 0.f;
  seg_reduce(valid ? d : -1, valid, h2, h2sum);
}

// ------------------------- final gather / reduce -----------------------------
// 32 threads per node: 16 float4-threads for x-max half, 16 for en-sum half.
__global__ void __launch_bounds__(256) gather_kernel(
    const int2* __restrict__ csr, const int* __restrict__ offsets,
    const float* __restrict__ gp, const float* __restrict__ h2sum,
    const float* __restrict__ tW3, const float* __restrict__ tb3,
    float* __restrict__ out) {
  __shared__ float sW3[2048 + 64];
  for (int t = threadIdx.x; t < 2048; t += 256) sW3[t] = tW3[t];
  for (int t = threadIdx.x; t < 64; t += 256) sW3[2048 + t] = tb3[t];
  __syncthreads();
  int n = blockIdx.x * 8 + (threadIdx.x >> 5);
  int l = threadIdx.x & 31;
  int half = l >> 4, j4 = l & 15;
  int off = half * 64 + j4 * 4;
  int o0 = offsets[n], o1 = offsets[n + 1];
  int deg = o1 - o0;

  const float NEG = -3.402823466e38f;
  float4 mx = make_float4(NEG, NEG, NEG, NEG);
  float4 sm4 = make_float4(0.f, 0.f, 0.f, 0.f);
  for (int t = o0; t < o1; ++t) {
    int s = csr[t].x;
    float4 v = *(const float4*)(gp + (long)s * 128 + off);
    mx.x = fmaxf(mx.x, v.x); mx.y = fmaxf(mx.y, v.y);
    mx.z = fmaxf(mx.z, v.z); mx.w = fmaxf(mx.w, v.w);
    sm4.x += v.x; sm4.y += v.y; sm4.z += v.z; sm4.w += v.w;
  }

  float4 r;
  if (half == 0) {
    float4 a = *(const float4*)(out + (long)n * 128 + off);
    bool has = deg > 0;
    r.x = has ? a.x + mx.x : 0.f;
    r.y = has ? a.y + mx.y : 0.f;
    r.z = has ? a.z + mx.z : 0.f;
    r.w = has ? a.w + mx.w : 0.f;
  } else {
    int jj = j4 * 4;
    float w30 = 0.f, w31 = 0.f, w32 = 0.f, w33 = 0.f;
    const float* h2r = h2sum + (long)n * 32;
#pragma unroll
    for (int k = 0; k < 32; ++k) {
      float h = h2r[k];
      const float* wrow = &sW3[k * 64 + jj];
      w30 += h * wrow[0]; w31 += h * wrow[1];
      w32 += h * wrow[2]; w33 += h * wrow[3];
    }
    float dg = (float)deg;
    float inv = 1.f / fmaxf(dg, 1.f);
    r.x = (sm4.x + w30 + dg * sW3[2048 + jj + 0]) * inv;
    r.y = (sm4.y + w31 + dg * sW3[2048 + jj + 1]) * inv;
    r.z = (sm4.z + w32 + dg * sW3[2048 + jj + 2]) * inv;
    r.w = (sm4.w + w33 + dg * sW3[2048 + jj + 3]) * inv;
  }
  *(float4*)(out + (long)n * 128 + off) = r;
}

// ---------------------------------- launch -----------------------------------
extern "C" void kernel_launch(void* const* d_in, const int* in_sizes, int n_in,
                              void* d_out, int out_size, void* d_ws,
                              size_t ws_size, hipStream_t stream) {
  const float* x   = (const float*)d_in[0];
  const float* en  = (const float*)d_in[1];
  const int* src   = (const int*)d_in[2];
  const int* dst   = (const int*)d_in[3];
  const float* thW = (const float*)d_in[4];
  const float* thB = (const float*)d_in[5];
  const float* phW = (const float*)d_in[6];
  const float* phB = (const float*)d_in[7];
  const float* tW0 = (const float*)d_in[8];
  const float* tb0 = (const float*)d_in[9];
  const float* tW1 = (const float*)d_in[10];
  const float* tb1 = (const float*)d_in[11];
  const float* tW2 = (const float*)d_in[12];
  const float* tb2 = (const float*)d_in[13];
  const float* tW3 = (const float*)d_in[14];
  const float* tb3 = (const float*)d_in[15];
  const float* pW0 = (const float*)d_in[16];
  const float* pb0 = (const float*)d_in[17];
  const float* pW1 = (const float*)d_in[18];
  const float* pb1 = (const float*)d_in[19];
  const float* pW2 = (const float*)d_in[20];
  const float* pb2 = (const float*)d_in[21];
  const float* pW3 = (const float*)d_in[22];
  const float* pb3 = (const float*)d_in[23];

  float* out = (float*)d_out;
  float* ws  = (float*)d_ws;
  // ws layout (floats): gp[N*128], u[N*64], h2sum[N*32], wbuf[WB_SZ], ints
  float* gp     = ws;                           // 6,400,000
  float* u      = ws + (long)N_NODES * 128;     // 3,200,000
  float* h2sum  = ws + (long)N_NODES * 192;     // 1,600,000
  float* wbuf   = ws + (long)N_NODES * 224;     // 26,624
  int* iw       = (int*)(wbuf + WB_SZ);
  int2* csr     = (int2*)iw;                    // E pairs (src,dst)
  int* counts   = iw + 2 * N_EDGES;             // N (becomes cursor)
  int* offsets  = counts + N_NODES;             // N+1
  // total ws ≈ 51.7 MB

  hipMemsetAsync(counts, 0, N_NODES * sizeof(int), stream);
  hipMemsetAsync(h2sum, 0, (size_t)N_NODES * 32 * sizeof(float), stream);
  prep_kernel<<<(WB_SZ + 255) / 256, 256, 0, stream>>>(
      tW1, pW1, thW, phW, tW0, pW0, pW3, wbuf);
  count_kernel<<<(N_EDGES + 255) / 256, 256, 0, stream>>>(dst, counts);
  scan_kernel<<<1, 1024, 0, stream>>>(counts, offsets);
  scatter_kernel<<<(N_EDGES + 255) / 256, 256, 0, stream>>>(
      src, dst, counts, csr);
  node_kernel<<<2 * NBX, 512, 0, stream>>>(
      x, en, wbuf, thB, phB, pb0, pb1, pW2, pb2, pb3, out, gp, u);
  mlp_edge_kernel<<<(N_EDGES + 255) / 256, 256, 0, stream>>>(
      u, csr, tb0, wbuf + WB_W1T, tb1, tW2, tb2, h2sum);
  gather_kernel<<<N_NODES / 8, 256, 0, stream>>>(
      csr, offsets, gp, h2sum, tW3, tb3, out);
}

// Round 6
// 940.677 us; speedup vs baseline: 1.1838x; 1.1838x over previous
//
#include <hip/hip_runtime.h>

#define N_NODES 50000
#define N_EDGES 800000

// ---------- shared 32->64->128->32 MLP block (relative smem layout) ----------
// (used only by node_kernel for the pen path)
constexpr int M_W0T = 0;        // [64][32] transposed
constexpr int M_B0  = 2048;     // 64
constexpr int M_W1T = 2112;     // [128][64] transposed
constexpr int M_B1  = 10304;    // 128
constexpr int M_W2  = 10432;    // [128][32] natural
constexpr int M_B2  = 14528;    // 32
constexpr int M_SZ  = 14560;    // floats

__device__ __forceinline__ void stage_mlp(float* sm,
    const float* __restrict__ W0, const float* __restrict__ b0,
    const float* __restrict__ W1, const float* __restrict__ b1,
    const float* __restrict__ W2, const float* __restrict__ b2,
    int tid, int nthr) {
  for (int t = tid; t < 2048; t += nthr) {
    int j = t >> 5, k = t & 31;
    sm[M_W0T + t] = W0[k * 64 + j];          // W0 is [32][64]
  }
  for (int t = tid; t < 8192; t += nthr) {
    int k2 = t >> 6, j = t & 63;
    sm[M_W1T + t] = W1[j * 128 + k2];        // W1 is [64][128]
  }
  for (int t = tid; t < 4096; t += nthr) sm[M_W2 + t] = W2[t];
  for (int t = tid; t < 64; t += nthr)  sm[M_B0 + t] = b0[t];
  for (int t = tid; t < 128; t += nthr) sm[M_B1 + t] = b1[t];
  for (int t = tid; t < 32; t += nthr)  sm[M_B2 + t] = b2[t];
}

__device__ __forceinline__ void mlp_core(const float* sm, const float den[32],
                                         float h2[32]) {
  float h0[64];
#pragma unroll
  for (int j = 0; j < 64; ++j) {
    float a = sm[M_B0 + j];
#pragma unroll
    for (int k = 0; k < 32; ++k) a += den[k] * sm[M_W0T + j * 32 + k];
    h0[j] = fmaxf(a, 0.f);
  }
#pragma unroll
  for (int j = 0; j < 32; ++j) h2[j] = sm[M_B2 + j];
  for (int k2 = 0; k2 < 128; ++k2) {
    float t = sm[M_B1 + k2];
#pragma unroll
    for (int j = 0; j < 64; ++j) t += h0[j] * sm[M_W1T + k2 * 64 + j];
    t = fmaxf(t, 0.f);
#pragma unroll
    for (int j = 0; j < 32; ++j) h2[j] += t * sm[M_W2 + k2 * 32 + j];
  }
#pragma unroll
  for (int j = 0; j < 32; ++j) h2[j] = fmaxf(h2[j], 0.f);
}

// ------------------------------- CSR build ----------------------------------
__global__ void __launch_bounds__(256) count_kernel(const int* __restrict__ dst,
                                                    int* __restrict__ counts) {
  int e = blockIdx.x * 256 + threadIdx.x;
  if (e < N_EDGES) atomicAdd(&counts[dst[e]], 1);
}

__global__ void __launch_bounds__(1024) scan_kernel(int* __restrict__ counts,
                                                    int* __restrict__ offsets) {
  __shared__ int ps[1024];
  const int PER = (N_NODES + 1023) / 1024;  // 49
  int tid = threadIdx.x;
  int base = tid * PER;
  int s = 0;
  for (int i = 0; i < PER; ++i) {
    int idx = base + i;
    if (idx < N_NODES) s += counts[idx];
  }
  ps[tid] = s;
  __syncthreads();
  for (int off = 1; off < 1024; off <<= 1) {
    int t = (tid >= off) ? ps[tid - off] : 0;
    __syncthreads();
    ps[tid] += t;
    __syncthreads();
  }
  int run = ps[tid] - s;
  for (int i = 0; i < PER; ++i) {
    int idx = base + i;
    if (idx < N_NODES) {
      int c = counts[idx];
      offsets[idx] = run;
      counts[idx] = run;  // cursor for scatter
      run += c;
    }
  }
  if (tid == 1023) offsets[N_NODES] = ps[1023];
}

__global__ void __launch_bounds__(256) scatter_kernel(
    const int* __restrict__ src, const int* __restrict__ dst,
    int* __restrict__ cursor, int* __restrict__ csr_src,
    int* __restrict__ csr_dst) {
  int e = blockIdx.x * 256 + threadIdx.x;
  if (e >= N_EDGES) return;
  int d = dst[e];
  int slot = atomicAdd(&cursor[d], 1);
  csr_src[slot] = src[e];
  csr_dst[slot] = d;
}

// W1T[k2][j] = W1[j][k2]  (theta-MLP layer-1 weights, transposed to ws)
__global__ void __launch_bounds__(256) prep_kernel(
    const float* __restrict__ W1, float* __restrict__ W1T) {
  int t = blockIdx.x * 256 + threadIdx.x;
  if (t < 8192) {
    int k2 = t >> 6, j = t & 63;
    W1T[t] = W1[j * 128 + k2];
  }
}

// ------------------------------ node kernel ---------------------------------
// out[n][0:64]  = a[n]   = x@thW + thB
// gp[n][0:64]   = g[n]   = x@phW + phB - x@thW
// gp[n][64:128] = pen[n] = full 4-layer pen MLP(en[n])
// u[n][0:64]    = en @ tW0   (theta-MLP layer-0 partial, no bias/relu)
constexpr int NK_THT = 0;        // 2048
constexpr int NK_PHT = 2048;     // 2048
constexpr int NK_TW0 = 4096;     // 2048 (theta-MLP W0 transposed)
constexpr int NK_THB = 6144;     // 64
constexpr int NK_PHB = 6208;     // 64
constexpr int NK_B3  = 6272;     // 64
constexpr int NK_MLP = 6336;     // 14560 (pen MLP)
constexpr int NK_W3T = 20896;    // 2048 (pen W3 transposed)
constexpr int NK_SZ  = 22944;    // 91.8 KB

__global__ void __launch_bounds__(512) node_kernel(
    const float* __restrict__ x, const float* __restrict__ en,
    const float* __restrict__ thW, const float* __restrict__ thB,
    const float* __restrict__ phW, const float* __restrict__ phB,
    const float* __restrict__ tW0,
    const float* __restrict__ pW0, const float* __restrict__ pb0,
    const float* __restrict__ pW1, const float* __restrict__ pb1,
    const float* __restrict__ pW2, const float* __restrict__ pb2,
    const float* __restrict__ pW3, const float* __restrict__ pb3,
    float* __restrict__ out, float* __restrict__ gp, float* __restrict__ u) {
  __shared__ __align__(16) float sm[NK_SZ];
  const int tid = threadIdx.x;
  for (int t = tid; t < 2048; t += 512) {
    int j = t >> 5, k = t & 31;
    sm[NK_THT + t] = thW[k * 64 + j];
    sm[NK_PHT + t] = phW[k * 64 + j];
    sm[NK_TW0 + t] = tW0[k * 64 + j];
    sm[NK_W3T + t] = pW3[k * 64 + j];
  }
  for (int t = tid; t < 64; t += 512) {
    sm[NK_THB + t] = thB[t];
    sm[NK_PHB + t] = phB[t];
    sm[NK_B3 + t] = pb3[t];
  }
  stage_mlp(sm + NK_MLP, pW0, pb0, pW1, pb1, pW2, pb2, tid, 512);
  __syncthreads();
  int n = blockIdx.x * 512 + tid;
  if (n >= N_NODES) return;

  float xv[32];
  {
    const float4* p = (const float4*)(x + (long)n * 32);
#pragma unroll
    for (int q = 0; q < 8; ++q) {
      float4 v = p[q];
      xv[q * 4 + 0] = v.x; xv[q * 4 + 1] = v.y;
      xv[q * 4 + 2] = v.z; xv[q * 4 + 3] = v.w;
    }
  }
  float* ao = out + (long)n * 128;
  float* go = gp + (long)n * 128;
  for (int j = 0; j < 64; ++j) {
    float dth = 0.f, dph = 0.f;
#pragma unroll
    for (int k = 0; k < 32; ++k) {
      dth += xv[k] * sm[NK_THT + j * 32 + k];
      dph += xv[k] * sm[NK_PHT + j * 32 + k];
    }
    ao[j] = sm[NK_THB + j] + dth;          // a
    go[j] = sm[NK_PHB + j] + dph - dth;    // g
  }

  float ev[32];
  {
    const float4* p = (const float4*)(en + (long)n * 32);
#pragma unroll
    for (int q = 0; q < 8; ++q) {
      float4 v = p[q];
      ev[q * 4 + 0] = v.x; ev[q * 4 + 1] = v.y;
      ev[q * 4 + 2] = v.z; ev[q * 4 + 3] = v.w;
    }
  }
  // u[n] = en @ tW0 (no bias/relu)
  float* uo = u + (long)n * 64;
  for (int j = 0; j < 64; ++j) {
    float a = 0.f;
#pragma unroll
    for (int k = 0; k < 32; ++k) a += ev[k] * sm[NK_TW0 + j * 32 + k];
    uo[j] = a;
  }
  float h2p[32];
  mlp_core(sm + NK_MLP, ev, h2p);
  for (int j = 0; j < 64; ++j) {
    float o = sm[NK_B3 + j];
#pragma unroll
    for (int k = 0; k < 32; ++k) o += h2p[k] * sm[NK_W3T + j * 32 + k];
    go[64 + j] = o;                        // pen
  }
}

// -------- per-edge theta MLP (layers 1,2) — scalar (SGPR) weights ------------
// (round-3 structure verbatim: 1 edge/thread, VGPR 64, zero LDS)
__device__ __forceinline__ void seg_reduce(int d, bool valid, float h2[32],
                                           float* __restrict__ h2sum) {
  int lane = threadIdx.x & 63;
  int dprev = __shfl_up(d, 1);
  bool head = (lane == 0) || (dprev != d);
  int seg = head ? lane : 0;
#pragma unroll
  for (int off = 1; off < 64; off <<= 1) {
    int t = __shfl_up(seg, off);
    if (lane >= off) seg = max(seg, t);
  }
#pragma unroll
  for (int off = 1; off < 64; off <<= 1) {
    bool take = (lane - off) >= seg;
#pragma unroll
    for (int k = 0; k < 32; ++k) {
      float t = __shfl_up(h2[k], off);
      h2[k] += take ? t : 0.f;
    }
  }
  int dnext = __shfl_down(d, 1);
  bool tail = (lane == 63) || (dnext != d);
  if (valid && tail) {
    float* hs = h2sum + (long)d * 32;
#pragma unroll
    for (int k = 0; k < 32; ++k) atomicAdd(&hs[k], h2[k]);
  }
}

__global__ void __launch_bounds__(256) mlp_edge_kernel(
    const float* __restrict__ u,
    const int* __restrict__ csr_src, const int* __restrict__ csr_dst,
    const float* __restrict__ b0g,
    const float* __restrict__ W1T,   // [128][64] pre-transposed (in ws)
    const float* __restrict__ b1g,
    const float* __restrict__ W2,    // [128][32] natural
    const float* __restrict__ b2g,
    float* __restrict__ h2sum) {
  long slot = (long)blockIdx.x * 256 + threadIdx.x;
  const bool valid = slot < N_EDGES;
  const int idx = valid ? (int)slot : 0;
  const int s = csr_src[idx], d = csr_dst[idx];

  // h0 = relu(u[d] - u[s] + b0)   (b0 reads are wave-uniform -> SGPR)
  float h0[64];
  {
    const float4* ud4 = (const float4*)(u + (long)d * 64);
    const float4* us4 = (const float4*)(u + (long)s * 64);
#pragma unroll
    for (int q = 0; q < 16; ++q) {
      float4 a = ud4[q], b = us4[q];
      h0[q * 4 + 0] = fmaxf(a.x - b.x + b0g[q * 4 + 0], 0.f);
      h0[q * 4 + 1] = fmaxf(a.y - b.y + b0g[q * 4 + 1], 0.f);
      h0[q * 4 + 2] = fmaxf(a.z - b.z + b0g[q * 4 + 2], 0.f);
      h0[q * 4 + 3] = fmaxf(a.w - b.w + b0g[q * 4 + 3], 0.f);
    }
  }

  float h2[32];
#pragma unroll
  for (int c = 0; c < 32; ++c) h2[c] = b2g[c];

  // k2-outer: W1T row (256B) and W2 row (128B) are contiguous, wave-uniform
  // -> s_load_dwordx16 on the scalar pipe; zero LDS traffic.
#pragma unroll 2
  for (int k2 = 0; k2 < 128; ++k2) {
    const float* wr = W1T + k2 * 64;
    float t0 = b1g[k2], t1 = 0.f, t2 = 0.f, t3 = 0.f;
#pragma unroll
    for (int j = 0; j < 16; ++j) {
      t0 += h0[j]      * wr[j];
      t1 += h0[j + 16] * wr[j + 16];
      t2 += h0[j + 32] * wr[j + 32];
      t3 += h0[j + 48] * wr[j + 48];
    }
    float t = fmaxf((t0 + t1) + (t2 + t3), 0.f);
    const float* w2r = W2 + k2 * 32;
#pragma unroll
    for (int c = 0; c < 32; ++c) h2[c] += t * w2r[c];
  }

#pragma unroll
  for (int c = 0; c < 32; ++c) h2[c] = valid ? fmaxf(h2[c], 0.f) : 0.f;
  seg_reduce(valid ? d : -1, valid, h2, h2sum);
}

// ------------------------- final gather / reduce -----------------------------
// 32 threads per node: 16 float4-threads for x-max half, 16 for en-sum half.
__global__ void __launch_bounds__(256) gather_kernel(
    const int* __restrict__ csr_src, const int* __restrict__ offsets,
    const float* __restrict__ gp, const float* __restrict__ h2sum,
    const float* __restrict__ tW3, const float* __restrict__ tb3,
    float* __restrict__ out) {
  __shared__ float sW3[2048 + 64];
  for (int t = threadIdx.x; t < 2048; t += 256) sW3[t] = tW3[t];
  for (int t = threadIdx.x; t < 64; t += 256) sW3[2048 + t] = tb3[t];
  __syncthreads();
  int n = blockIdx.x * 8 + (threadIdx.x >> 5);
  int l = threadIdx.x & 31;
  int half = l >> 4, j4 = l & 15;
  int off = half * 64 + j4 * 4;
  int o0 = offsets[n], o1 = offsets[n + 1];
  int deg = o1 - o0;

  const float NEG = -3.402823466e38f;
  float4 mx = make_float4(NEG, NEG, NEG, NEG);
  float4 sm4 = make_float4(0.f, 0.f, 0.f, 0.f);
  for (int t = o0; t < o1; ++t) {
    int s = csr_src[t];
    float4 v = *(const float4*)(gp + (long)s * 128 + off);
    mx.x = fmaxf(mx.x, v.x); mx.y = fmaxf(mx.y, v.y);
    mx.z = fmaxf(mx.z, v.z); mx.w = fmaxf(mx.w, v.w);
    sm4.x += v.x; sm4.y += v.y; sm4.z += v.z; sm4.w += v.w;
  }

  float4 r;
  if (half == 0) {
    float4 a = *(const float4*)(out + (long)n * 128 + off);
    bool has = deg > 0;
    r.x = has ? a.x + mx.x : 0.f;
    r.y = has ? a.y + mx.y : 0.f;
    r.z = has ? a.z + mx.z : 0.f;
    r.w = has ? a.w + mx.w : 0.f;
  } else {
    int jj = j4 * 4;
    float w30 = 0.f, w31 = 0.f, w32 = 0.f, w33 = 0.f;
    const float* h2r = h2sum + (long)n * 32;
#pragma unroll
    for (int k = 0; k < 32; ++k) {
      float h = h2r[k];
      const float* wrow = &sW3[k * 64 + jj];
      w30 += h * wrow[0]; w31 += h * wrow[1];
      w32 += h * wrow[2]; w33 += h * wrow[3];
    }
    float dg = (float)deg;
    float inv = 1.f / fmaxf(dg, 1.f);
    r.x = (sm4.x + w30 + dg * sW3[2048 + jj + 0]) * inv;
    r.y = (sm4.y + w31 + dg * sW3[2048 + jj + 1]) * inv;
    r.z = (sm4.z + w32 + dg * sW3[2048 + jj + 2]) * inv;
    r.w = (sm4.w + w33 + dg * sW3[2048 + jj + 3]) * inv;
  }
  *(float4*)(out + (long)n * 128 + off) = r;
}

// ---------------------------------- launch -----------------------------------
extern "C" void kernel_launch(void* const* d_in, const int* in_sizes, int n_in,
                              void* d_out, int out_size, void* d_ws,
                              size_t ws_size, hipStream_t stream) {
  const float* x   = (const float*)d_in[0];
  const float* en  = (const float*)d_in[1];
  const int* src   = (const int*)d_in[2];
  const int* dst   = (const int*)d_in[3];
  const float* thW = (const float*)d_in[4];
  const float* thB = (const float*)d_in[5];
  const float* phW = (const float*)d_in[6];
  const float* phB = (const float*)d_in[7];
  const float* tW0 = (const float*)d_in[8];
  const float* tb0 = (const float*)d_in[9];
  const float* tW1 = (const float*)d_in[10];
  const float* tb1 = (const float*)d_in[11];
  const float* tW2 = (const float*)d_in[12];
  const float* tb2 = (const float*)d_in[13];
  const float* tW3 = (const float*)d_in[14];
  const float* tb3 = (const float*)d_in[15];
  const float* pW0 = (const float*)d_in[16];
  const float* pb0 = (const float*)d_in[17];
  const float* pW1 = (const float*)d_in[18];
  const float* pb1 = (const float*)d_in[19];
  const float* pW2 = (const float*)d_in[20];
  const float* pb2 = (const float*)d_in[21];
  const float* pW3 = (const float*)d_in[22];
  const float* pb3 = (const float*)d_in[23];

  float* out = (float*)d_out;
  float* ws  = (float*)d_ws;
  // ws layout (floats): gp[N*128], u[N*64], h2sum[N*32], w1t[8192], then ints
  float* gp     = ws;                           // 6,400,000
  float* u      = ws + (long)N_NODES * 128;     // 3,200,000
  float* h2sum  = ws + (long)N_NODES * 192;     // 1,600,000
  float* w1t    = ws + (long)N_NODES * 224;     // 8,192
  int* iw       = (int*)(w1t + 8192);
  int* csr_src  = iw;                           // E
  int* csr_dst  = iw + N_EDGES;                 // E
  int* counts   = iw + 2 * N_EDGES;             // N (becomes cursor)
  int* offsets  = counts + N_NODES;             // N+1
  // total ws ≈ 51.5 MB

  hipMemsetAsync(counts, 0, N_NODES * sizeof(int), stream);
  hipMemsetAsync(h2sum, 0, (size_t)N_NODES * 32 * sizeof(float), stream);
  prep_kernel<<<32, 256, 0, stream>>>(tW1, w1t);
  count_kernel<<<(N_EDGES + 255) / 256, 256, 0, stream>>>(dst, counts);
  scan_kernel<<<1, 1024, 0, stream>>>(counts, offsets);
  scatter_kernel<<<(N_EDGES + 255) / 256, 256, 0, stream>>>(
      src, dst, counts, csr_src, csr_dst);
  node_kernel<<<(N_NODES + 511) / 512, 512, 0, stream>>>(
      x, en, thW, thB, phW, phB, tW0, pW0, pb0, pW1, pb1, pW2, pb2, pW3, pb3,
      out, gp, u);
  mlp_edge_kernel<<<(N_EDGES + 255) / 256, 256, 0, stream>>>(
      u, csr_src, csr_dst, tb0, w1t, tb1, tW2, tb2, h2sum);
  gather_kernel<<<N_NODES / 8, 256, 0, stream>>>(
      csr_src, offsets, gp, h2sum, tW3, tb3, out);
}

// Round 7
// 559.648 us; speedup vs baseline: 1.9898x; 1.6808x over previous
//
#include <hip/hip_runtime.h>

#define N_NODES 50000
#define N_EDGES 800000

typedef __attribute__((ext_vector_type(8))) short short8v;
typedef __attribute__((ext_vector_type(4))) float f32x4;

// ---------- shared 32->64->128->32 MLP block (relative smem layout) ----------
// (used only by node_kernel for the pen path)
constexpr int M_W0T = 0;        // [64][32] transposed
constexpr int M_B0  = 2048;     // 64
constexpr int M_W1T = 2112;     // [128][64] transposed
constexpr int M_B1  = 10304;    // 128
constexpr int M_W2  = 10432;    // [128][32] natural
constexpr int M_B2  = 14528;    // 32
constexpr int M_SZ  = 14560;    // floats

__device__ __forceinline__ void stage_mlp(float* sm,
    const float* __restrict__ W0, const float* __restrict__ b0,
    const float* __restrict__ W1, const float* __restrict__ b1,
    const float* __restrict__ W2, const float* __restrict__ b2,
    int tid, int nthr) {
  for (int t = tid; t < 2048; t += nthr) {
    int j = t >> 5, k = t & 31;
    sm[M_W0T + t] = W0[k * 64 + j];          // W0 is [32][64]
  }
  for (int t = tid; t < 8192; t += nthr) {
    int k2 = t >> 6, j = t & 63;
    sm[M_W1T + t] = W1[j * 128 + k2];        // W1 is [64][128]
  }
  for (int t = tid; t < 4096; t += nthr) sm[M_W2 + t] = W2[t];
  for (int t = tid; t < 64; t += nthr)  sm[M_B0 + t] = b0[t];
  for (int t = tid; t < 128; t += nthr) sm[M_B1 + t] = b1[t];
  for (int t = tid; t < 32; t += nthr)  sm[M_B2 + t] = b2[t];
}

__device__ __forceinline__ void mlp_core(const float* sm, const float den[32],
                                         float h2[32]) {
  float h0[64];
#pragma unroll
  for (int j = 0; j < 64; ++j) {
    float a = sm[M_B0 + j];
#pragma unroll
    for (int k = 0; k < 32; ++k) a += den[k] * sm[M_W0T + j * 32 + k];
    h0[j] = fmaxf(a, 0.f);
  }
#pragma unroll
  for (int j = 0; j < 32; ++j) h2[j] = sm[M_B2 + j];
  for (int k2 = 0; k2 < 128; ++k2) {
    float t = sm[M_B1 + k2];
#pragma unroll
    for (int j = 0; j < 64; ++j) t += h0[j] * sm[M_W1T + k2 * 64 + j];
    t = fmaxf(t, 0.f);
#pragma unroll
    for (int j = 0; j < 32; ++j) h2[j] += t * sm[M_W2 + k2 * 32 + j];
  }
#pragma unroll
  for (int j = 0; j < 32; ++j) h2[j] = fmaxf(h2[j], 0.f);
}

// ------------------------------- CSR build ----------------------------------
__global__ void __launch_bounds__(256) count_kernel(const int* __restrict__ dst,
                                                    int* __restrict__ counts) {
  int e = blockIdx.x * 256 + threadIdx.x;
  if (e < N_EDGES) atomicAdd(&counts[dst[e]], 1);
}

__global__ void __launch_bounds__(1024) scan_kernel(int* __restrict__ counts,
                                                    int* __restrict__ offsets) {
  __shared__ int ps[1024];
  const int PER = (N_NODES + 1023) / 1024;  // 49
  int tid = threadIdx.x;
  int base = tid * PER;
  int s = 0;
  for (int i = 0; i < PER; ++i) {
    int idx = base + i;
    if (idx < N_NODES) s += counts[idx];
  }
  ps[tid] = s;
  __syncthreads();
  for (int off = 1; off < 1024; off <<= 1) {
    int t = (tid >= off) ? ps[tid - off] : 0;
    __syncthreads();
    ps[tid] += t;
    __syncthreads();
  }
  int run = ps[tid] - s;
  for (int i = 0; i < PER; ++i) {
    int idx = base + i;
    if (idx < N_NODES) {
      int c = counts[idx];
      offsets[idx] = run;
      counts[idx] = run;  // cursor for scatter
      run += c;
    }
  }
  if (tid == 1023) offsets[N_NODES] = ps[1023];
}

__global__ void __launch_bounds__(256) scatter_kernel(
    const int* __restrict__ src, const int* __restrict__ dst,
    int* __restrict__ cursor, int* __restrict__ csr_src,
    int* __restrict__ csr_dst) {
  int e = blockIdx.x * 256 + threadIdx.x;
  if (e >= N_EDGES) return;
  int d = dst[e];
  int slot = atomicAdd(&cursor[d], 1);
  csr_src[slot] = src[e];
  csr_dst[slot] = d;
}

// ---------------- weight split-bf16 fragment packing --------------------------
// wp (ushort) layout:
//   [0,8192)      W1 hi frags : fi = r*2+f (r=0..7 k2-tile, f=0..1 j-frag)
//                 elem (fi, lane, j) = W1T[k2 = r*16+(lane&15)][jg = f*32+(lane>>4)*8+j]
//   [8192,16384)  W1 lo frags
//   [16384,20480) W2 hi frags : fi2 = t*4+f2 (t=0..1 out-tile, f2=0..3 k2-frag)
//                 elem = W2T[c = t*16+(lane&15)][k2 = f2*32+(lane>>4)*8+j]
//   [20480,24576) W2 lo frags
__device__ __forceinline__ ushort bf16hi(float v) {
  return (ushort)(__float_as_uint(v) >> 16);
}

__global__ void __launch_bounds__(256) pack_kernel(
    const float* __restrict__ tW1, const float* __restrict__ tW2,
    ushort* __restrict__ wp) {
  int t = blockIdx.x * 256 + threadIdx.x;
  if (t >= 12288) return;
  float v;
  int hi_off, lo_off;
  if (t < 8192) {
    int fi = t >> 9, lane = (t >> 3) & 63, j = t & 7;
    int r = fi >> 1, f = fi & 1;
    int k2 = r * 16 + (lane & 15);
    int jg = f * 32 + (lane >> 4) * 8 + j;
    v = tW1[jg * 128 + k2];                 // W1 is [64][128]
    hi_off = t; lo_off = 8192 + t;
  } else {
    int t2 = t - 8192;
    int fi = t2 >> 9, lane = (t2 >> 3) & 63, j = t2 & 7;
    int tt = fi >> 2, f2 = fi & 3;
    int cc = tt * 16 + (lane & 15);
    int k2 = f2 * 32 + (lane >> 4) * 8 + j;
    v = tW2[k2 * 32 + cc];                  // W2 is [128][32]
    hi_off = 16384 + t2; lo_off = 20480 + t2;
  }
  ushort h = bf16hi(v);
  float hf = __uint_as_float((unsigned)h << 16);
  ushort l = bf16hi(v - hf);
  wp[hi_off] = h;
  wp[lo_off] = l;
}

// ------------------------------ node kernel ---------------------------------
constexpr int NK_THT = 0;        // 2048
constexpr int NK_PHT = 2048;     // 2048
constexpr int NK_TW0 = 4096;     // 2048 (theta-MLP W0 transposed)
constexpr int NK_THB = 6144;     // 64
constexpr int NK_PHB = 6208;     // 64
constexpr int NK_B3  = 6272;     // 64
constexpr int NK_MLP = 6336;     // 14560 (pen MLP)
constexpr int NK_W3T = 20896;    // 2048 (pen W3 transposed)
constexpr int NK_SZ  = 22944;    // 91.8 KB

__global__ void __launch_bounds__(512) node_kernel(
    const float* __restrict__ x, const float* __restrict__ en,
    const float* __restrict__ thW, const float* __restrict__ thB,
    const float* __restrict__ phW, const float* __restrict__ phB,
    const float* __restrict__ tW0,
    const float* __restrict__ pW0, const float* __restrict__ pb0,
    const float* __restrict__ pW1, const float* __restrict__ pb1,
    const float* __restrict__ pW2, const float* __restrict__ pb2,
    const float* __restrict__ pW3, const float* __restrict__ pb3,
    float* __restrict__ out, float* __restrict__ gp, float* __restrict__ u) {
  __shared__ __align__(16) float sm[NK_SZ];
  const int tid = threadIdx.x;
  for (int t = tid; t < 2048; t += 512) {
    int j = t >> 5, k = t & 31;
    sm[NK_THT + t] = thW[k * 64 + j];
    sm[NK_PHT + t] = phW[k * 64 + j];
    sm[NK_TW0 + t] = tW0[k * 64 + j];
    sm[NK_W3T + t] = pW3[k * 64 + j];
  }
  for (int t = tid; t < 64; t += 512) {
    sm[NK_THB + t] = thB[t];
    sm[NK_PHB + t] = phB[t];
    sm[NK_B3 + t] = pb3[t];
  }
  stage_mlp(sm + NK_MLP, pW0, pb0, pW1, pb1, pW2, pb2, tid, 512);
  __syncthreads();
  int n = blockIdx.x * 512 + tid;
  if (n >= N_NODES) return;

  float xv[32];
  {
    const float4* p = (const float4*)(x + (long)n * 32);
#pragma unroll
    for (int q = 0; q < 8; ++q) {
      float4 v = p[q];
      xv[q * 4 + 0] = v.x; xv[q * 4 + 1] = v.y;
      xv[q * 4 + 2] = v.z; xv[q * 4 + 3] = v.w;
    }
  }
  float* ao = out + (long)n * 128;
  float* go = gp + (long)n * 128;
  for (int j = 0; j < 64; ++j) {
    float dth = 0.f, dph = 0.f;
#pragma unroll
    for (int k = 0; k < 32; ++k) {
      dth += xv[k] * sm[NK_THT + j * 32 + k];
      dph += xv[k] * sm[NK_PHT + j * 32 + k];
    }
    ao[j] = sm[NK_THB + j] + dth;          // a
    go[j] = sm[NK_PHB + j] + dph - dth;    // g
  }

  float ev[32];
  {
    const float4* p = (const float4*)(en + (long)n * 32);
#pragma unroll
    for (int q = 0; q < 8; ++q) {
      float4 v = p[q];
      ev[q * 4 + 0] = v.x; ev[q * 4 + 1] = v.y;
      ev[q * 4 + 2] = v.z; ev[q * 4 + 3] = v.w;
    }
  }
  float* uo = u + (long)n * 64;
  for (int j = 0; j < 64; ++j) {
    float a = 0.f;
#pragma unroll
    for (int k = 0; k < 32; ++k) a += ev[k] * sm[NK_TW0 + j * 32 + k];
    uo[j] = a;
  }
  float h2p[32];
  mlp_core(sm + NK_MLP, ev, h2p);
  for (int j = 0; j < 64; ++j) {
    float o = sm[NK_B3 + j];
#pragma unroll
    for (int k = 0; k < 32; ++k) o += h2p[k] * sm[NK_W3T + j * 32 + k];
    go[64 + j] = o;                        // pen
  }
}

// ----------- per-edge theta MLP (layers 1,2) via split-bf16 MFMA -------------
// Wave = 16 consecutive CSR slots. lane: q = lane>>4 (k-slice group),
// c = lane&15 (edge column). GEMM1: C1[k2][e] = W1T·H0; GEMM2: C2[c][e]=W2T·H1.
// C/D layout (HW-verified): col = lane&15, row = (lane>>4)*4 + reg.
__global__ void __launch_bounds__(256) mlp_edge_kernel(
    const float* __restrict__ u,
    const int* __restrict__ csr_src, const int* __restrict__ csr_dst,
    const float* __restrict__ b0g, const float* __restrict__ b1g,
    const float* __restrict__ b2g,
    const ushort* __restrict__ wp,
    float* __restrict__ h2sum) {
  __shared__ __align__(16) ushort lds[24576];   // 48 KB
  {
    const uint4* s4 = (const uint4*)wp;
    uint4* d4 = (uint4*)lds;
    for (int i = threadIdx.x; i < 3072; i += 256) d4[i] = s4[i];
  }
  __syncthreads();

  const int lane = threadIdx.x & 63;
  const int q = lane >> 4, c = lane & 15;
  const int wv = threadIdx.x >> 6;
  const int e = (blockIdx.x * 4 + wv) * 16 + c;   // always < N_EDGES (exact fit)
  const int s = csr_src[e], d = csr_dst[e];

  const short8v* W1HI = (const short8v*)(lds);
  const short8v* W1LO = (const short8v*)(lds + 8192);
  const short8v* W2HI = (const short8v*)(lds + 16384);
  const short8v* W2LO = (const short8v*)(lds + 20480);

  // ---- build B(h0) frags: frag f covers j = f*32 + q*8 .. +7 ----
  short8v bh0, bl0, bh1, bl1;
  {
    const float* ud = u + (long)d * 64 + q * 8;
    const float* us = u + (long)s * 64 + q * 8;
    const float* bp = b0g + q * 8;
#pragma unroll
    for (int f = 0; f < 2; ++f) {
      float4 d0 = *(const float4*)(ud + f * 32);
      float4 d1 = *(const float4*)(ud + f * 32 + 4);
      float4 s0 = *(const float4*)(us + f * 32);
      float4 s1 = *(const float4*)(us + f * 32 + 4);
      float4 c0 = *(const float4*)(bp + f * 32);
      float4 c1 = *(const float4*)(bp + f * 32 + 4);
      float v[8];
      v[0] = fmaxf(d0.x - s0.x + c0.x, 0.f);
      v[1] = fmaxf(d0.y - s0.y + c0.y, 0.f);
      v[2] = fmaxf(d0.z - s0.z + c0.z, 0.f);
      v[3] = fmaxf(d0.w - s0.w + c0.w, 0.f);
      v[4] = fmaxf(d1.x - s1.x + c1.x, 0.f);
      v[5] = fmaxf(d1.y - s1.y + c1.y, 0.f);
      v[6] = fmaxf(d1.z - s1.z + c1.z, 0.f);
      v[7] = fmaxf(d1.w - s1.w + c1.w, 0.f);
      short8v hh, ll;
#pragma unroll
      for (int j = 0; j < 8; ++j) {
        unsigned uv = __float_as_uint(v[j]);
        hh[j] = (short)(uv >> 16);
        float hf = __uint_as_float(uv & 0xFFFF0000u);
        ll[j] = (short)(__float_as_uint(v[j] - hf) >> 16);
      }
      if (f == 0) { bh0 = hh; bl0 = ll; } else { bh1 = hh; bl1 = ll; }
    }
  }

  // ---- GEMM1: acc[r] = b1 tile + W1T·h0 (split: hi*hi + lo*hi + hi*lo) ----
  f32x4 acc[8];
#pragma unroll
  for (int r = 0; r < 8; ++r)
    acc[r] = *(const f32x4*)(b1g + r * 16 + q * 4);
#pragma unroll
  for (int r = 0; r < 8; ++r) {
    short8v ah0 = W1HI[(2 * r) * 64 + lane];
    short8v ah1 = W1HI[(2 * r + 1) * 64 + lane];
    short8v al0 = W1LO[(2 * r) * 64 + lane];
    short8v al1 = W1LO[(2 * r + 1) * 64 + lane];
    acc[r] = __builtin_amdgcn_mfma_f32_16x16x32_bf16(ah0, bh0, acc[r], 0, 0, 0);
    acc[r] = __builtin_amdgcn_mfma_f32_16x16x32_bf16(ah1, bh1, acc[r], 0, 0, 0);
    acc[r] = __builtin_amdgcn_mfma_f32_16x16x32_bf16(al0, bh0, acc[r], 0, 0, 0);
    acc[r] = __builtin_amdgcn_mfma_f32_16x16x32_bf16(al1, bh1, acc[r], 0, 0, 0);
    acc[r] = __builtin_amdgcn_mfma_f32_16x16x32_bf16(ah0, bl0, acc[r], 0, 0, 0);
    acc[r] = __builtin_amdgcn_mfma_f32_16x16x32_bf16(ah1, bl1, acc[r], 0, 0, 0);
  }
  float h1v[8][4];
#pragma unroll
  for (int r = 0; r < 8; ++r)
#pragma unroll
    for (int g = 0; g < 4; ++g) h1v[r][g] = fmaxf(acc[r][g], 0.f);

  // ---- redistribute h1 into B2 frags via shuffles ----
  // need h1[k2 = f2*32 + 8q + jj][c]; owner lane = c + 16*(2(q&1)+(jj>>2)),
  // owner reg = acc[2f2 + (q>>1)][jj&3]
  const int qh = q >> 1;
  const int srcA = c + 32 * (q & 1);
  const int srcB = srcA + 16;
  short8v b2h[4], b2l[4];
#pragma unroll
  for (int f2 = 0; f2 < 4; ++f2) {
    float ev[8];
#pragma unroll
    for (int g = 0; g < 4; ++g) {
      float x0 = __shfl(h1v[2 * f2][g], srcA);
      float x1 = __shfl(h1v[2 * f2 + 1][g], srcA);
      ev[g] = qh ? x1 : x0;
      float y0 = __shfl(h1v[2 * f2][g], srcB);
      float y1 = __shfl(h1v[2 * f2 + 1][g], srcB);
      ev[4 + g] = qh ? y1 : y0;
    }
    short8v hh, ll;
#pragma unroll
    for (int j = 0; j < 8; ++j) {
      unsigned uv = __float_as_uint(ev[j]);
      hh[j] = (short)(uv >> 16);
      float hf = __uint_as_float(uv & 0xFFFF0000u);
      ll[j] = (short)(__float_as_uint(ev[j] - hf) >> 16);
    }
    b2h[f2] = hh; b2l[f2] = ll;
  }

  // ---- GEMM2: 2 out-tiles × 4 k-frags × 3 split ----
  f32x4 a20 = *(const f32x4*)(b2g + q * 4);
  f32x4 a21 = *(const f32x4*)(b2g + 16 + q * 4);
#pragma unroll
  for (int f2 = 0; f2 < 4; ++f2) {
    short8v ah = W2HI[f2 * 64 + lane];
    short8v al = W2LO[f2 * 64 + lane];
    a20 = __builtin_amdgcn_mfma_f32_16x16x32_bf16(ah, b2h[f2], a20, 0, 0, 0);
    a20 = __builtin_amdgcn_mfma_f32_16x16x32_bf16(al, b2h[f2], a20, 0, 0, 0);
    a20 = __builtin_amdgcn_mfma_f32_16x16x32_bf16(ah, b2l[f2], a20, 0, 0, 0);
    short8v ah1 = W2HI[(4 + f2) * 64 + lane];
    short8v al1 = W2LO[(4 + f2) * 64 + lane];
    a21 = __builtin_amdgcn_mfma_f32_16x16x32_bf16(ah1, b2h[f2], a21, 0, 0, 0);
    a21 = __builtin_amdgcn_mfma_f32_16x16x32_bf16(al1, b2h[f2], a21, 0, 0, 0);
    a21 = __builtin_amdgcn_mfma_f32_16x16x32_bf16(ah1, b2l[f2], a21, 0, 0, 0);
  }
  float h2v[8];
#pragma unroll
  for (int g = 0; g < 4; ++g) {
    h2v[g] = fmaxf(a20[g], 0.f);
    h2v[4 + g] = fmaxf(a21[g], 0.f);
  }

  // ---- 16-wide segmented inclusive sum along edge columns ----
  int dp = __shfl_up(d, 1, 16);
  bool head = (c == 0) || (dp != d);
  int seg = head ? c : 0;
#pragma unroll
  for (int off = 1; off < 16; off <<= 1) {
    int t = __shfl_up(seg, off, 16);
    if (c >= off) seg = max(seg, t);
  }
#pragma unroll
  for (int off = 1; off < 16; off <<= 1) {
    bool take = (c - off) >= seg;
#pragma unroll
    for (int k = 0; k < 8; ++k) {
      float t = __shfl_up(h2v[k], off, 16);
      if (take) h2v[k] += t;
    }
  }
  int dn = __shfl_down(d, 1, 16);
  bool tail = (c == 15) || (dn != d);
  if (tail) {
    float* hs = h2sum + (long)d * 32 + q * 4;   // channel = t*16 + q*4 + g
#pragma unroll
    for (int g = 0; g < 4; ++g) atomicAdd(&hs[g], h2v[g]);
#pragma unroll
    for (int g = 0; g < 4; ++g) atomicAdd(&hs[16 + g], h2v[4 + g]);
  }
}

// ------------------------- final gather / reduce -----------------------------
__global__ void __launch_bounds__(256) gather_kernel(
    const int* __restrict__ csr_src, const int* __restrict__ offsets,
    const float* __restrict__ gp, const float* __restrict__ h2sum,
    const float* __restrict__ tW3, const float* __restrict__ tb3,
    float* __restrict__ out) {
  __shared__ float sW3[2048 + 64];
  for (int t = threadIdx.x; t < 2048; t += 256) sW3[t] = tW3[t];
  for (int t = threadIdx.x; t < 64; t += 256) sW3[2048 + t] = tb3[t];
  __syncthreads();
  int n = blockIdx.x * 8 + (threadIdx.x >> 5);
  int l = threadIdx.x & 31;
  int half = l >> 4, j4 = l & 15;
  int off = half * 64 + j4 * 4;
  int o0 = offsets[n], o1 = offsets[n + 1];
  int deg = o1 - o0;

  const float NEG = -3.402823466e38f;
  float4 mx = make_float4(NEG, NEG, NEG, NEG);
  float4 sm4 = make_float4(0.f, 0.f, 0.f, 0.f);
  for (int t = o0; t < o1; ++t) {
    int s = csr_src[t];
    float4 v = *(const float4*)(gp + (long)s * 128 + off);
    mx.x = fmaxf(mx.x, v.x); mx.y = fmaxf(mx.y, v.y);
    mx.z = fmaxf(mx.z, v.z); mx.w = fmaxf(mx.w, v.w);
    sm4.x += v.x; sm4.y += v.y; sm4.z += v.z; sm4.w += v.w;
  }

  float4 r;
  if (half == 0) {
    float4 a = *(const float4*)(out + (long)n * 128 + off);
    bool has = deg > 0;
    r.x = has ? a.x + mx.x : 0.f;
    r.y = has ? a.y + mx.y : 0.f;
    r.z = has ? a.z + mx.z : 0.f;
    r.w = has ? a.w + mx.w : 0.f;
  } else {
    int jj = j4 * 4;
    float w30 = 0.f, w31 = 0.f, w32 = 0.f, w33 = 0.f;
    const float* h2r = h2sum + (long)n * 32;
#pragma unroll
    for (int k = 0; k < 32; ++k) {
      float h = h2r[k];
      const float* wrow = &sW3[k * 64 + jj];
      w30 += h * wrow[0]; w31 += h * wrow[1];
      w32 += h * wrow[2]; w33 += h * wrow[3];
    }
    float dg = (float)deg;
    float inv = 1.f / fmaxf(dg, 1.f);
    r.x = (sm4.x + w30 + dg * sW3[2048 + jj + 0]) * inv;
    r.y = (sm4.y + w31 + dg * sW3[2048 + jj + 1]) * inv;
    r.z = (sm4.z + w32 + dg * sW3[2048 + jj + 2]) * inv;
    r.w = (sm4.w + w33 + dg * sW3[2048 + jj + 3]) * inv;
  }
  *(float4*)(out + (long)n * 128 + off) = r;
}

// ---------------------------------- launch -----------------------------------
extern "C" void kernel_launch(void* const* d_in, const int* in_sizes, int n_in,
                              void* d_out, int out_size, void* d_ws,
                              size_t ws_size, hipStream_t stream) {
  const float* x   = (const float*)d_in[0];
  const float* en  = (const float*)d_in[1];
  const int* src   = (const int*)d_in[2];
  const int* dst   = (const int*)d_in[3];
  const float* thW = (const float*)d_in[4];
  const float* thB = (const float*)d_in[5];
  const float* phW = (const float*)d_in[6];
  const float* phB = (const float*)d_in[7];
  const float* tW0 = (const float*)d_in[8];
  const float* tb0 = (const float*)d_in[9];
  const float* tW1 = (const float*)d_in[10];
  const float* tb1 = (const float*)d_in[11];
  const float* tW2 = (const float*)d_in[12];
  const float* tb2 = (const float*)d_in[13];
  const float* tW3 = (const float*)d_in[14];
  const float* tb3 = (const float*)d_in[15];
  const float* pW0 = (const float*)d_in[16];
  const float* pb0 = (const float*)d_in[17];
  const float* pW1 = (const float*)d_in[18];
  const float* pb1 = (const float*)d_in[19];
  const float* pW2 = (const float*)d_in[20];
  const float* pb2 = (const float*)d_in[21];
  const float* pW3 = (const float*)d_in[22];
  const float* pb3 = (const float*)d_in[23];

  float* out = (float*)d_out;
  float* ws  = (float*)d_ws;
  // ws layout (floats): gp[N*128], u[N*64], h2sum[N*32], wpack[12288], ints
  float* gp     = ws;                           // 6,400,000
  float* u      = ws + (long)N_NODES * 128;     // 3,200,000
  float* h2sum  = ws + (long)N_NODES * 192;     // 1,600,000
  float* wpf    = ws + (long)N_NODES * 224;     // 12,288 (24576 ushorts)
  ushort* wp    = (ushort*)wpf;
  int* iw       = (int*)(wpf + 12288);
  int* csr_src  = iw;                           // E
  int* csr_dst  = iw + N_EDGES;                 // E
  int* counts   = iw + 2 * N_EDGES;             // N (becomes cursor)
  int* offsets  = counts + N_NODES;             // N+1
  // total ws ≈ 51.7 MB

  hipMemsetAsync(counts, 0, N_NODES * sizeof(int), stream);
  hipMemsetAsync(h2sum, 0, (size_t)N_NODES * 32 * sizeof(float), stream);
  pack_kernel<<<48, 256, 0, stream>>>(tW1, tW2, wp);
  count_kernel<<<(N_EDGES + 255) / 256, 256, 0, stream>>>(dst, counts);
  scan_kernel<<<1, 1024, 0, stream>>>(counts, offsets);
  scatter_kernel<<<(N_EDGES + 255) / 256, 256, 0, stream>>>(
      src, dst, counts, csr_src, csr_dst);
  node_kernel<<<(N_NODES + 511) / 512, 512, 0, stream>>>(
      x, en, thW, thB, phW, phB, tW0, pW0, pb0, pW1, pb1, pW2, pb2, pW3, pb3,
      out, gp, u);
  mlp_edge_kernel<<<N_EDGES / 64, 256, 0, stream>>>(
      u, csr_src, csr_dst, tb0, tb1, tb2, wp, h2sum);
  gather_kernel<<<N_NODES / 8, 256, 0, stream>>>(
      csr_src, offsets, gp, h2sum, tW3, tb3, out);
}

// Round 8
// 523.025 us; speedup vs baseline: 2.1291x; 1.0700x over previous
//
#include <hip/hip_runtime.h>

#define N_NODES 50000
#define N_EDGES 800000

typedef __attribute__((ext_vector_type(8))) short short8v;
typedef __attribute__((ext_vector_type(4))) float f32x4;

// ---------- shared 32->64->128->32 MLP block (relative smem layout) ----------
constexpr int M_W0T = 0;        // [64][32] transposed
constexpr int M_B0  = 2048;     // 64
constexpr int M_W1T = 2112;     // [128][64] transposed
constexpr int M_B1  = 10304;    // 128
constexpr int M_W2  = 10432;    // [128][32] natural
constexpr int M_B2  = 14528;    // 32
constexpr int M_SZ  = 14560;    // floats

__device__ __forceinline__ void stage_mlp(float* sm,
    const float* __restrict__ W0, const float* __restrict__ b0,
    const float* __restrict__ W1, const float* __restrict__ b1,
    const float* __restrict__ W2, const float* __restrict__ b2,
    int tid, int nthr) {
  for (int t = tid; t < 2048; t += nthr) {
    int j = t >> 5, k = t & 31;
    sm[M_W0T + t] = W0[k * 64 + j];          // W0 is [32][64]
  }
  for (int t = tid; t < 8192; t += nthr) {
    int k2 = t >> 6, j = t & 63;
    sm[M_W1T + t] = W1[j * 128 + k2];        // W1 is [64][128]
  }
  for (int t = tid; t < 4096; t += nthr) sm[M_W2 + t] = W2[t];
  for (int t = tid; t < 64; t += nthr)  sm[M_B0 + t] = b0[t];
  for (int t = tid; t < 128; t += nthr) sm[M_B1 + t] = b1[t];
  for (int t = tid; t < 32; t += nthr)  sm[M_B2 + t] = b2[t];
}

__device__ __forceinline__ void mlp_core(const float* sm, const float den[32],
                                         float h2[32]) {
  float h0[64];
#pragma unroll
  for (int j = 0; j < 64; ++j) {
    float a = sm[M_B0 + j];
#pragma unroll
    for (int k = 0; k < 32; ++k) a += den[k] * sm[M_W0T + j * 32 + k];
    h0[j] = fmaxf(a, 0.f);
  }
#pragma unroll
  for (int j = 0; j < 32; ++j) h2[j] = sm[M_B2 + j];
  for (int k2 = 0; k2 < 128; ++k2) {
    float t = sm[M_B1 + k2];
#pragma unroll
    for (int j = 0; j < 64; ++j) t += h0[j] * sm[M_W1T + k2 * 64 + j];
    t = fmaxf(t, 0.f);
#pragma unroll
    for (int j = 0; j < 32; ++j) h2[j] += t * sm[M_W2 + k2 * 32 + j];
  }
#pragma unroll
  for (int j = 0; j < 32; ++j) h2[j] = fmaxf(h2[j], 0.f);
}

// ------------------------------- CSR build ----------------------------------
__global__ void __launch_bounds__(256) count_kernel(const int* __restrict__ dst,
                                                    int* __restrict__ counts) {
  int e = blockIdx.x * 256 + threadIdx.x;
  if (e < N_EDGES) atomicAdd(&counts[dst[e]], 1);
}

// shfl-based scan: wave-level inclusive scan + 16-partial combine (2 barriers)
__global__ void __launch_bounds__(1024) scan_kernel(int* __restrict__ counts,
                                                    int* __restrict__ offsets) {
  __shared__ int wsum[16];
  const int PER = (N_NODES + 1023) / 1024;  // 49
  int tid = threadIdx.x;
  int base = tid * PER;
  int s = 0;
  for (int i = 0; i < PER; ++i) {
    int idx = base + i;
    if (idx < N_NODES) s += counts[idx];
  }
  int lane = tid & 63, w = tid >> 6;
  int v = s;
#pragma unroll
  for (int off = 1; off < 64; off <<= 1) {
    int t = __shfl_up(v, off);
    if (lane >= off) v += t;
  }
  if (lane == 63) wsum[w] = v;
  __syncthreads();
  int wpre = 0;
#pragma unroll
  for (int i = 0; i < 16; ++i) {
    int t = wsum[i];
    if (i < w) wpre += t;
  }
  int incl = v + wpre;     // inclusive scan of per-thread sums
  int run = incl - s;      // exclusive prefix for this thread's chunk
  for (int i = 0; i < PER; ++i) {
    int idx = base + i;
    if (idx < N_NODES) {
      int c = counts[idx];
      offsets[idx] = run;
      counts[idx] = run;  // cursor for scatter
      run += c;
    }
  }
  if (tid == 1023) offsets[N_NODES] = incl;
}

__global__ void __launch_bounds__(256) scatter_kernel(
    const int* __restrict__ src, const int* __restrict__ dst,
    int* __restrict__ cursor, int* __restrict__ csr_src,
    int* __restrict__ csr_dst) {
  int e = blockIdx.x * 256 + threadIdx.x;
  if (e >= N_EDGES) return;
  int d = dst[e];
  int slot = atomicAdd(&cursor[d], 1);
  csr_src[slot] = src[e];
  csr_dst[slot] = d;
}

// ---------------- weight split-bf16 fragment packing --------------------------
__device__ __forceinline__ ushort bf16hi(float v) {
  return (ushort)(__float_as_uint(v) >> 16);
}

__global__ void __launch_bounds__(256) pack_kernel(
    const float* __restrict__ tW1, const float* __restrict__ tW2,
    ushort* __restrict__ wp) {
  int t = blockIdx.x * 256 + threadIdx.x;
  if (t >= 12288) return;
  float v;
  int hi_off, lo_off;
  if (t < 8192) {
    int fi = t >> 9, lane = (t >> 3) & 63, j = t & 7;
    int r = fi >> 1, f = fi & 1;
    int k2 = r * 16 + (lane & 15);
    int jg = f * 32 + (lane >> 4) * 8 + j;
    v = tW1[jg * 128 + k2];                 // W1 is [64][128]
    hi_off = t; lo_off = 8192 + t;
  } else {
    int t2 = t - 8192;
    int fi = t2 >> 9, lane = (t2 >> 3) & 63, j = t2 & 7;
    int tt = fi >> 2, f2 = fi & 3;
    int cc = tt * 16 + (lane & 15);
    int k2 = f2 * 32 + (lane >> 4) * 8 + j;
    v = tW2[k2 * 32 + cc];                  // W2 is [128][32]
    hi_off = 16384 + t2; lo_off = 20480 + t2;
  }
  ushort h = bf16hi(v);
  float hf = __uint_as_float((unsigned)h << 16);
  ushort l = bf16hi(v - hf);
  wp[hi_off] = h;
  wp[lo_off] = l;
}

// ------------------------------ node kernels ---------------------------------
// x path: out[n][0:64]=a=x@thW+thB ; gp[n][0:64]=g=x@phW+phB-x@thW
constexpr int XK_THT = 0;      // 2048
constexpr int XK_PHT = 2048;   // 2048
constexpr int XK_THB = 4096;   // 64
constexpr int XK_PHB = 4160;   // 64
constexpr int XK_SZ  = 4224;   // 16.9 KB

__global__ void __launch_bounds__(256) node_x_kernel(
    const float* __restrict__ x,
    const float* __restrict__ thW, const float* __restrict__ thB,
    const float* __restrict__ phW, const float* __restrict__ phB,
    float* __restrict__ out, float* __restrict__ gp) {
  __shared__ __align__(16) float sm[XK_SZ];
  const int tid = threadIdx.x;
  for (int t = tid; t < 2048; t += 256) {
    int j = t >> 5, k = t & 31;
    sm[XK_THT + t] = thW[k * 64 + j];
    sm[XK_PHT + t] = phW[k * 64 + j];
  }
  for (int t = tid; t < 64; t += 256) {
    sm[XK_THB + t] = thB[t];
    sm[XK_PHB + t] = phB[t];
  }
  __syncthreads();
  int n = blockIdx.x * 256 + tid;
  if (n >= N_NODES) return;

  float xv[32];
  {
    const float4* p = (const float4*)(x + (long)n * 32);
#pragma unroll
    for (int q = 0; q < 8; ++q) {
      float4 v = p[q];
      xv[q * 4 + 0] = v.x; xv[q * 4 + 1] = v.y;
      xv[q * 4 + 2] = v.z; xv[q * 4 + 3] = v.w;
    }
  }
  float* ao = out + (long)n * 128;
  float* go = gp + (long)n * 128;
  for (int j = 0; j < 64; ++j) {
    float dth = 0.f, dph = 0.f;
#pragma unroll
    for (int k = 0; k < 32; ++k) {
      dth += xv[k] * sm[XK_THT + j * 32 + k];
      dph += xv[k] * sm[XK_PHT + j * 32 + k];
    }
    ao[j] = sm[XK_THB + j] + dth;          // a
    go[j] = sm[XK_PHB + j] + dph - dth;    // g
  }
}

// en path: u[n]=en@tW0 ; gp[n][64:128]=pen MLP(en[n])
constexpr int EK_TW0 = 0;        // 2048
constexpr int EK_MLP = 2048;     // 14560
constexpr int EK_W3T = 16608;    // 2048
constexpr int EK_B3  = 18656;    // 64
constexpr int EK_SZ  = 18720;    // 74.9 KB

__global__ void __launch_bounds__(256) node_en_kernel(
    const float* __restrict__ en, const float* __restrict__ tW0,
    const float* __restrict__ pW0, const float* __restrict__ pb0,
    const float* __restrict__ pW1, const float* __restrict__ pb1,
    const float* __restrict__ pW2, const float* __restrict__ pb2,
    const float* __restrict__ pW3, const float* __restrict__ pb3,
    float* __restrict__ gp, float* __restrict__ u) {
  __shared__ __align__(16) float sm[EK_SZ];
  const int tid = threadIdx.x;
  for (int t = tid; t < 2048; t += 256) {
    int j = t >> 5, k = t & 31;
    sm[EK_TW0 + t] = tW0[k * 64 + j];
    sm[EK_W3T + t] = pW3[k * 64 + j];
  }
  for (int t = tid; t < 64; t += 256) sm[EK_B3 + t] = pb3[t];
  stage_mlp(sm + EK_MLP, pW0, pb0, pW1, pb1, pW2, pb2, tid, 256);
  __syncthreads();
  int n = blockIdx.x * 256 + tid;
  if (n >= N_NODES) return;

  float ev[32];
  {
    const float4* p = (const float4*)(en + (long)n * 32);
#pragma unroll
    for (int q = 0; q < 8; ++q) {
      float4 v = p[q];
      ev[q * 4 + 0] = v.x; ev[q * 4 + 1] = v.y;
      ev[q * 4 + 2] = v.z; ev[q * 4 + 3] = v.w;
    }
  }
  float* uo = u + (long)n * 64;
  for (int j = 0; j < 64; ++j) {
    float a = 0.f;
#pragma unroll
    for (int k = 0; k < 32; ++k) a += ev[k] * sm[EK_TW0 + j * 32 + k];
    uo[j] = a;
  }
  float h2p[32];
  mlp_core(sm + EK_MLP, ev, h2p);
  float* go = gp + (long)n * 128 + 64;
  for (int j = 0; j < 64; ++j) {
    float o = sm[EK_B3 + j];
#pragma unroll
    for (int k = 0; k < 32; ++k) o += h2p[k] * sm[EK_W3T + j * 32 + k];
    go[j] = o;                             // pen
  }
}

// ----------- per-edge theta MLP (layers 1,2) via split-bf16 MFMA -------------
// Wave = 16 consecutive CSR slots. 512-thr blocks (8 waves) -> 2 blocks/CU,
// 4 waves/SIMD. C/D layout (HW-verified): col=lane&15, row=(lane>>4)*4+reg.
__global__ void __launch_bounds__(512) mlp_edge_kernel(
    const float* __restrict__ u,
    const int* __restrict__ csr_src, const int* __restrict__ csr_dst,
    const float* __restrict__ b0g, const float* __restrict__ b1g,
    const float* __restrict__ b2g,
    const ushort* __restrict__ wp,
    float* __restrict__ h2sum) {
  __shared__ __align__(16) ushort lds[24576];   // 48 KB
  {
    const uint4* s4 = (const uint4*)wp;
    uint4* d4 = (uint4*)lds;
    for (int i = threadIdx.x; i < 3072; i += 512) d4[i] = s4[i];
  }
  __syncthreads();

  const int lane = threadIdx.x & 63;
  const int q = lane >> 4, c = lane & 15;
  const int wv = threadIdx.x >> 6;
  const int e = (blockIdx.x * 8 + wv) * 16 + c;   // exact fit: 6250*128=800000
  const int s = csr_src[e], d = csr_dst[e];

  const short8v* W1HI = (const short8v*)(lds);
  const short8v* W1LO = (const short8v*)(lds + 8192);
  const short8v* W2HI = (const short8v*)(lds + 16384);
  const short8v* W2LO = (const short8v*)(lds + 20480);

  // ---- build B(h0) frags: frag f covers j = f*32 + q*8 .. +7 ----
  short8v bh0, bl0, bh1, bl1;
  {
    const float* ud = u + (long)d * 64 + q * 8;
    const float* us = u + (long)s * 64 + q * 8;
    const float* bp = b0g + q * 8;
#pragma unroll
    for (int f = 0; f < 2; ++f) {
      float4 d0 = *(const float4*)(ud + f * 32);
      float4 d1 = *(const float4*)(ud + f * 32 + 4);
      float4 s0 = *(const float4*)(us + f * 32);
      float4 s1 = *(const float4*)(us + f * 32 + 4);
      float4 c0 = *(const float4*)(bp + f * 32);
      float4 c1 = *(const float4*)(bp + f * 32 + 4);
      float v[8];
      v[0] = fmaxf(d0.x - s0.x + c0.x, 0.f);
      v[1] = fmaxf(d0.y - s0.y + c0.y, 0.f);
      v[2] = fmaxf(d0.z - s0.z + c0.z, 0.f);
      v[3] = fmaxf(d0.w - s0.w + c0.w, 0.f);
      v[4] = fmaxf(d1.x - s1.x + c1.x, 0.f);
      v[5] = fmaxf(d1.y - s1.y + c1.y, 0.f);
      v[6] = fmaxf(d1.z - s1.z + c1.z, 0.f);
      v[7] = fmaxf(d1.w - s1.w + c1.w, 0.f);
      short8v hh, ll;
#pragma unroll
      for (int j = 0; j < 8; ++j) {
        unsigned uv = __float_as_uint(v[j]);
        hh[j] = (short)(uv >> 16);
        float hf = __uint_as_float(uv & 0xFFFF0000u);
        ll[j] = (short)(__float_as_uint(v[j] - hf) >> 16);
      }
      if (f == 0) { bh0 = hh; bl0 = ll; } else { bh1 = hh; bl1 = ll; }
    }
  }

  // ---- GEMM1: acc[r] = b1 tile + W1T·h0 (hi*hi + lo*hi + hi*lo) ----
  f32x4 acc[8];
#pragma unroll
  for (int r = 0; r < 8; ++r)
    acc[r] = *(const f32x4*)(b1g + r * 16 + q * 4);
#pragma unroll
  for (int r = 0; r < 8; ++r) {
    short8v ah0 = W1HI[(2 * r) * 64 + lane];
    short8v ah1 = W1HI[(2 * r + 1) * 64 + lane];
    short8v al0 = W1LO[(2 * r) * 64 + lane];
    short8v al1 = W1LO[(2 * r + 1) * 64 + lane];
    acc[r] = __builtin_amdgcn_mfma_f32_16x16x32_bf16(ah0, bh0, acc[r], 0, 0, 0);
    acc[r] = __builtin_amdgcn_mfma_f32_16x16x32_bf16(ah1, bh1, acc[r], 0, 0, 0);
    acc[r] = __builtin_amdgcn_mfma_f32_16x16x32_bf16(al0, bh0, acc[r], 0, 0, 0);
    acc[r] = __builtin_amdgcn_mfma_f32_16x16x32_bf16(al1, bh1, acc[r], 0, 0, 0);
    acc[r] = __builtin_amdgcn_mfma_f32_16x16x32_bf16(ah0, bl0, acc[r], 0, 0, 0);
    acc[r] = __builtin_amdgcn_mfma_f32_16x16x32_bf16(ah1, bl1, acc[r], 0, 0, 0);
  }
  float h1v[8][4];
#pragma unroll
  for (int r = 0; r < 8; ++r)
#pragma unroll
    for (int g = 0; g < 4; ++g) h1v[r][g] = fmaxf(acc[r][g], 0.f);

  // ---- redistribute h1 into B2 frags via shuffles ----
  const int qh = q >> 1;
  const int srcA = c + 32 * (q & 1);
  const int srcB = srcA + 16;
  short8v b2h[4], b2l[4];
#pragma unroll
  for (int f2 = 0; f2 < 4; ++f2) {
    float ev[8];
#pragma unroll
    for (int g = 0; g < 4; ++g) {
      float x0 = __shfl(h1v[2 * f2][g], srcA);
      float x1 = __shfl(h1v[2 * f2 + 1][g], srcA);
      ev[g] = qh ? x1 : x0;
      float y0 = __shfl(h1v[2 * f2][g], srcB);
      float y1 = __shfl(h1v[2 * f2 + 1][g], srcB);
      ev[4 + g] = qh ? y1 : y0;
    }
    short8v hh, ll;
#pragma unroll
    for (int j = 0; j < 8; ++j) {
      unsigned uv = __float_as_uint(ev[j]);
      hh[j] = (short)(uv >> 16);
      float hf = __uint_as_float(uv & 0xFFFF0000u);
      ll[j] = (short)(__float_as_uint(ev[j] - hf) >> 16);
    }
    b2h[f2] = hh; b2l[f2] = ll;
  }

  // ---- GEMM2: 2 out-tiles × 4 k-frags × 3 split ----
  f32x4 a20 = *(const f32x4*)(b2g + q * 4);
  f32x4 a21 = *(const f32x4*)(b2g + 16 + q * 4);
#pragma unroll
  for (int f2 = 0; f2 < 4; ++f2) {
    short8v ah = W2HI[f2 * 64 + lane];
    short8v al = W2LO[f2 * 64 + lane];
    a20 = __builtin_amdgcn_mfma_f32_16x16x32_bf16(ah, b2h[f2], a20, 0, 0, 0);
    a20 = __builtin_amdgcn_mfma_f32_16x16x32_bf16(al, b2h[f2], a20, 0, 0, 0);
    a20 = __builtin_amdgcn_mfma_f32_16x16x32_bf16(ah, b2l[f2], a20, 0, 0, 0);
    short8v ah1 = W2HI[(4 + f2) * 64 + lane];
    short8v al1 = W2LO[(4 + f2) * 64 + lane];
    a21 = __builtin_amdgcn_mfma_f32_16x16x32_bf16(ah1, b2h[f2], a21, 0, 0, 0);
    a21 = __builtin_amdgcn_mfma_f32_16x16x32_bf16(al1, b2h[f2], a21, 0, 0, 0);
    a21 = __builtin_amdgcn_mfma_f32_16x16x32_bf16(ah1, b2l[f2], a21, 0, 0, 0);
  }
  float h2v[8];
#pragma unroll
  for (int g = 0; g < 4; ++g) {
    h2v[g] = fmaxf(a20[g], 0.f);
    h2v[4 + g] = fmaxf(a21[g], 0.f);
  }

  // ---- 16-wide segmented inclusive sum along edge columns ----
  int dp = __shfl_up(d, 1, 16);
  bool head = (c == 0) || (dp != d);
  int seg = head ? c : 0;
#pragma unroll
  for (int off = 1; off < 16; off <<= 1) {
    int t = __shfl_up(seg, off, 16);
    if (c >= off) seg = max(seg, t);
  }
#pragma unroll
  for (int off = 1; off < 16; off <<= 1) {
    bool take = (c - off) >= seg;
#pragma unroll
    for (int k = 0; k < 8; ++k) {
      float t = __shfl_up(h2v[k], off, 16);
      if (take) h2v[k] += t;
    }
  }
  int dn = __shfl_down(d, 1, 16);
  bool tail = (c == 15) || (dn != d);
  if (tail) {
    float* hs = h2sum + (long)d * 32 + q * 4;   // channel = t*16 + q*4 + g
#pragma unroll
    for (int g = 0; g < 4; ++g) atomicAdd(&hs[g], h2v[g]);
#pragma unroll
    for (int g = 0; g < 4; ++g) atomicAdd(&hs[16 + g], h2v[4 + g]);
  }
}

// ------------------------- final gather / reduce -----------------------------
__global__ void __launch_bounds__(256) gather_kernel(
    const int* __restrict__ csr_src, const int* __restrict__ offsets,
    const float* __restrict__ gp, const float* __restrict__ h2sum,
    const float* __restrict__ tW3, const float* __restrict__ tb3,
    float* __restrict__ out) {
  __shared__ float sW3[2048 + 64];
  for (int t = threadIdx.x; t < 2048; t += 256) sW3[t] = tW3[t];
  for (int t = threadIdx.x; t < 64; t += 256) sW3[2048 + t] = tb3[t];
  __syncthreads();
  int n = blockIdx.x * 8 + (threadIdx.x >> 5);
  int l = threadIdx.x & 31;
  int half = l >> 4, j4 = l & 15;
  int off = half * 64 + j4 * 4;
  int o0 = offsets[n], o1 = offsets[n + 1];
  int deg = o1 - o0;

  const float NEG = -3.402823466e38f;
  float4 mx = make_float4(NEG, NEG, NEG, NEG);
  float4 sm4 = make_float4(0.f, 0.f, 0.f, 0.f);
  for (int t = o0; t < o1; ++t) {
    int s = csr_src[t];
    float4 v = *(const float4*)(gp + (long)s * 128 + off);
    mx.x = fmaxf(mx.x, v.x); mx.y = fmaxf(mx.y, v.y);
    mx.z = fmaxf(mx.z, v.z); mx.w = fmaxf(mx.w, v.w);
    sm4.x += v.x; sm4.y += v.y; sm4.z += v.z; sm4.w += v.w;
  }

  float4 r;
  if (half == 0) {
    float4 a = *(const float4*)(out + (long)n * 128 + off);
    bool has = deg > 0;
    r.x = has ? a.x + mx.x : 0.f;
    r.y = has ? a.y + mx.y : 0.f;
    r.z = has ? a.z + mx.z : 0.f;
    r.w = has ? a.w + mx.w : 0.f;
  } else {
    int jj = j4 * 4;
    float w30 = 0.f, w31 = 0.f, w32 = 0.f, w33 = 0.f;
    const float* h2r = h2sum + (long)n * 32;
#pragma unroll
    for (int k = 0; k < 32; ++k) {
      float h = h2r[k];
      const float* wrow = &sW3[k * 64 + jj];
      w30 += h * wrow[0]; w31 += h * wrow[1];
      w32 += h * wrow[2]; w33 += h * wrow[3];
    }
    float dg = (float)deg;
    float inv = 1.f / fmaxf(dg, 1.f);
    r.x = (sm4.x + w30 + dg * sW3[2048 + jj + 0]) * inv;
    r.y = (sm4.y + w31 + dg * sW3[2048 + jj + 1]) * inv;
    r.z = (sm4.z + w32 + dg * sW3[2048 + jj + 2]) * inv;
    r.w = (sm4.w + w33 + dg * sW3[2048 + jj + 3]) * inv;
  }
  *(float4*)(out + (long)n * 128 + off) = r;
}

// ---------------------------------- launch -----------------------------------
extern "C" void kernel_launch(void* const* d_in, const int* in_sizes, int n_in,
                              void* d_out, int out_size, void* d_ws,
                              size_t ws_size, hipStream_t stream) {
  const float* x   = (const float*)d_in[0];
  const float* en  = (const float*)d_in[1];
  const int* src   = (const int*)d_in[2];
  const int* dst   = (const int*)d_in[3];
  const float* thW = (const float*)d_in[4];
  const float* thB = (const float*)d_in[5];
  const float* phW = (const float*)d_in[6];
  const float* phB = (const float*)d_in[7];
  const float* tW0 = (const float*)d_in[8];
  const float* tb0 = (const float*)d_in[9];
  const float* tW1 = (const float*)d_in[10];
  const float* tb1 = (const float*)d_in[11];
  const float* tW2 = (const float*)d_in[12];
  const float* tb2 = (const float*)d_in[13];
  const float* tW3 = (const float*)d_in[14];
  const float* tb3 = (const float*)d_in[15];
  const float* pW0 = (const float*)d_in[16];
  const float* pb0 = (const float*)d_in[17];
  const float* pW1 = (const float*)d_in[18];
  const float* pb1 = (const float*)d_in[19];
  const float* pW2 = (const float*)d_in[20];
  const float* pb2 = (const float*)d_in[21];
  const float* pW3 = (const float*)d_in[22];
  const float* pb3 = (const float*)d_in[23];

  float* out = (float*)d_out;
  float* ws  = (float*)d_ws;
  // ws layout (floats): gp[N*128], u[N*64], h2sum[N*32], wpack[12288], ints
  float* gp     = ws;                           // 6,400,000
  float* u      = ws + (long)N_NODES * 128;     // 3,200,000
  float* h2sum  = ws + (long)N_NODES * 192;     // 1,600,000
  float* wpf    = ws + (long)N_NODES * 224;     // 12,288 (24576 ushorts)
  ushort* wp    = (ushort*)wpf;
  int* iw       = (int*)(wpf + 12288);
  int* csr_src  = iw;                           // E
  int* csr_dst  = iw + N_EDGES;                 // E
  int* counts   = iw + 2 * N_EDGES;             // N (becomes cursor)
  int* offsets  = counts + N_NODES;             // N+1
  // total ws ≈ 51.7 MB

  hipMemsetAsync(counts, 0, N_NODES * sizeof(int), stream);
  hipMemsetAsync(h2sum, 0, (size_t)N_NODES * 32 * sizeof(float), stream);
  pack_kernel<<<48, 256, 0, stream>>>(tW1, tW2, wp);
  count_kernel<<<(N_EDGES + 255) / 256, 256, 0, stream>>>(dst, counts);
  scan_kernel<<<1, 1024, 0, stream>>>(counts, offsets);
  scatter_kernel<<<(N_EDGES + 255) / 256, 256, 0, stream>>>(
      src, dst, counts, csr_src, csr_dst);
  node_x_kernel<<<(N_NODES + 255) / 256, 256, 0, stream>>>(
      x, thW, thB, phW, phB, out, gp);
  node_en_kernel<<<(N_NODES + 255) / 256, 256, 0, stream>>>(
      en, tW0, pW0, pb0, pW1, pb1, pW2, pb2, pW3, pb3, gp, u);
  mlp_edge_kernel<<<N_EDGES / 128, 512, 0, stream>>>(
      u, csr_src, csr_dst, tb0, tb1, tb2, wp, h2sum);
  gather_kernel<<<N_NODES / 8, 256, 0, stream>>>(
      csr_src, offsets, gp, h2sum, tW3, tb3, out);
}